// Round 7
// baseline (847.589 us; speedup 1.0000x reference)
//
#include <hip/hip_runtime.h>
#include <math.h>

// DomainTransformFilter on [8,3,1024,1024] f32.
// 3 iterations of {61-tap horizontal Gaussian, 61-tap vertical Gaussian},
// replicate padding, sigma = 10/20/40 (all ks=61). Edge-weight multiplies
// s = w/(w+1e-8) differ from 1.0 by <7.4e-8 and are dropped (validated:
// absmax 3.9e-3 from fp32 ordering only, threshold ~1.1e-2).
//
// Round-7 (= round-4 resubmitted after three infra timeouts): round-3
// structure (LDS-free, register-staged window, proven 76-step x 16-acc
// unrolled FMA loop) + __builtin_amdgcn_sched_barrier(0) between the
// staging burst and the compute loop. Round-3's counters (VGPR=76 < live
// set, VALUBusy 15%, no scratch) proved the compiler SANK the staged loads
// into the compute loop, recreating load->use latency chains. The
// sched_barrier pins "issue all loads, then compute": one ~600-cycle
// latency exposure per ~3900 VALU-cycles of FMAs, covered by ~4 waves/SIMD.

#define HH 1024
#define WW 1024
#define BB 8
#define CC 3
#define KS 61
#define HK 30

struct GW { float w[KS]; };   // by value -> kernarg -> SGPR-resident weights

// ---------------------------------------------------------------------------
// Horizontal conv. Thread = 16 consecutive outputs of one row.
// Block 256 thr = 16 rows x 16 segments (256 out cols). Grid flat 6144,
// XCD-chunked (y-strips fastest within an XCD). Window re-reads between
// overlapping segments are L1-served (per-wave working set ~5 KB).
// ---------------------------------------------------------------------------
__global__ __launch_bounds__(256) void hconv(const float* __restrict__ in,
                                             float* __restrict__ out, GW g) {
    const int f   = blockIdx.x;            // 0..6143
    const int c   = f & 7;                 // XCD (dispatch round-robin)
    const int idx = f >> 3;                // 0..767
    const int w0  = c * 768 + idx;         // work id, y-strip fastest
    const int yb  = w0 & 63;               // 64 strips of 16 rows
    const int r1  = w0 >> 6;
    const int xc  = r1 & 3;                // 4 chunks of 256 cols
    const int bc  = r1 >> 2;               // 0..23

    const int seg = threadIdx.x & 15;
    const int row = threadIdx.x >> 4;
    const int y   = yb * 16 + row;
    const int X   = xc * 256 + seg * 16;   // first output col
    const int x0  = X - 32;                // float4-aligned window start

    const float* __restrict__ srow = in + ((size_t)bc * HH + y) * WW;

    // stage window [X-32, X+48) = 80 floats = 20 float4 loads
    float v[80];
    #pragma unroll
    for (int m = 0; m < 20; ++m) {
        const int gx = x0 + 4 * m;
        float4 t;
        if (gx >= 0 && gx <= WW - 4) {
            t = *(const float4*)(srow + gx);
        } else {                           // replicate pad (edge blocks only)
            const int a0 = min(max(gx    , 0), WW - 1);
            const int a1 = min(max(gx + 1, 0), WW - 1);
            const int a2 = min(max(gx + 2, 0), WW - 1);
            const int a3 = min(max(gx + 3, 0), WW - 1);
            t = make_float4(srow[a0], srow[a1], srow[a2], srow[a3]);
        }
        v[4 * m + 0] = t.x; v[4 * m + 1] = t.y;
        v[4 * m + 2] = t.z; v[4 * m + 3] = t.w;
    }

    // Pin the schedule: all staging loads issue BEFORE any compute; the
    // compiler may not sink them into the FMA loop (round-3 failure mode).
    __builtin_amdgcn_sched_barrier(0);

    float acc[16];
    #pragma unroll
    for (int i = 0; i < 16; ++i) acc[i] = 0.f;

    // input x = x0 + (j+2) = X - 30 + j ; output i tap t = j - i
    #pragma unroll
    for (int j = 0; j < 76; ++j) {
        const float s = v[j + 2];
        #pragma unroll
        for (int i = 0; i < 16; ++i) {
            const int t = j - i;
            if (t >= 0 && t < KS)
                acc[i] = fmaf(g.w[t], s, acc[i]);
        }
    }

    float* drow = out + ((size_t)bc * HH + y) * WW + X;
    #pragma unroll
    for (int i = 0; i < 4; ++i)
        *(float4*)(drow + 4 * i) = make_float4(acc[4*i], acc[4*i+1],
                                               acc[4*i+2], acc[4*i+3]);
}

// ---------------------------------------------------------------------------
// Vertical conv. Thread = 16 consecutive outputs of one column.
// Block 256 thr = 256 cols. Grid flat 6144, XCD-chunked so one XCD sweeps
// Y over a fixed (256-col, bc) strip -> halo re-reads are private-L2 hits
// (proven: FETCH 138 MB vs 456 MB logical in round 1).
// ---------------------------------------------------------------------------
__global__ __launch_bounds__(256) void vconv(const float* __restrict__ in,
                                             float* __restrict__ out, GW g) {
    const int f   = blockIdx.x;            // 0..6143
    const int c   = f & 7;                 // XCD
    const int idx = f >> 3;                // 0..767
    const int w0  = c * 768 + idx;         // work id, Y fastest
    const int Yt  = w0 & 63;
    const int r1  = w0 >> 6;
    const int xq  = r1 & 3;
    const int bc  = r1 >> 2;

    const int x = xq * 256 + threadIdx.x;
    const int Y = Yt * 16;                 // first output row

    const float* __restrict__ src = in + (size_t)bc * (HH * (size_t)WW);

    // stage the 76-row window (row base wave-uniform -> SALU addressing;
    // each load is a fully coalesced 256 B wave read)
    float v[76];
    #pragma unroll
    for (int j = 0; j < 76; ++j) {
        int gy = Y - HK + j;
        gy = min(max(gy, 0), HH - 1);      // replicate pad, wave-uniform
        v[j] = src[(size_t)gy * WW + x];
    }

    __builtin_amdgcn_sched_barrier(0);     // loads first, then compute

    float acc[16];
    #pragma unroll
    for (int i = 0; i < 16; ++i) acc[i] = 0.f;

    #pragma unroll
    for (int j = 0; j < 76; ++j) {
        const float s = v[j];
        #pragma unroll
        for (int i = 0; i < 16; ++i) {
            const int t = j - i;
            if (t >= 0 && t < KS)
                acc[i] = fmaf(g.w[t], s, acc[i]);
        }
    }

    float* dst = out + (size_t)bc * (HH * (size_t)WW) + (size_t)Y * WW + x;
    #pragma unroll
    for (int i = 0; i < 16; ++i) dst[(size_t)i * WW] = acc[i];
}

// ---------------------------------------------------------------------------
static void fill_w(double sigma, GW* g) {
    double tmp[KS], s = 0.0;
    for (int k = 0; k < KS; ++k) {
        const double d = (double)(k - HK);
        tmp[k] = exp(-(d * d) / (2.0 * sigma * sigma));
        s += tmp[k];
    }
    for (int k = 0; k < KS; ++k) g->w[k] = (float)(tmp[k] / s);
}

extern "C" void kernel_launch(void* const* d_in, const int* in_sizes, int n_in,
                              void* d_out, int out_size, void* d_ws, size_t ws_size,
                              hipStream_t stream) {
    const float* input = (const float*)d_in[0];
    float* out = (float*)d_out;
    float* tmp = (float*)d_ws;                     // 96 MiB scratch

    GW g10, g20, g40;
    fill_w(10.0, &g10);
    fill_w(20.0, &g20);
    fill_w(40.0, &g40);

    const dim3 hb(256), hg(6144);          // flat, XCD-chunked decode
    const dim3 vb(256), vg(6144);

    hconv<<<hg, hb, 0, stream>>>(input, tmp, g10);
    vconv<<<vg, vb, 0, stream>>>(tmp, out, g10);
    hconv<<<hg, hb, 0, stream>>>(out, tmp, g20);
    vconv<<<vg, vb, 0, stream>>>(tmp, out, g20);
    hconv<<<hg, hb, 0, stream>>>(out, tmp, g40);
    vconv<<<vg, vb, 0, stream>>>(tmp, out, g40);
}

// Round 12
// 766.259 us; speedup vs baseline: 1.1061x; 1.1061x over previous
//
#include <hip/hip_runtime.h>
#include <math.h>

// DomainTransformFilter on [8,3,1024,1024] f32.
// Reference: 3 iterations of {61-tap H Gaussian, 61-tap V Gaussian},
// replicate pad, sigma=10/20/40. Edge-weight multiplies s=w/(w+1e-8) are
// within 7.4e-8 of 1 and dropped (validated: absmax 3.9e-3, thr ~1.1e-2).
//
// Round-12 (= fusion kernel, 4th submission; desk-checked 3x + OOB audit).
// ALGEBRAIC FUSION: row-ops commute with column-ops exactly (replicate pad
// included), so the pipeline equals (H40∘H20∘H10) then (V40∘V20∘V10):
// TWO image passes instead of six.
//  - Interior (x or y in [90,934)): no clamp fires in any stage, so the
//    composed operator is a plain 181-tap conv; weights = w10*w20*w40
//    (discrete conv, composed on host in double).
//  - Edge bands (90 px each side): iterated-clamp != direct-clamp conv, so
//    two small kernels reproduce the reference exactly: stage a 217-wide
//    strip in LDS and run the three 61-tap convs sequentially IN LDS
//    (150 -> 120 -> 90 outputs). Right edge via mirror (kernels symmetric).
// Why this beats per-pass tuning: every LDS variant was convoy-limited
// (stage->barrier->compute, VALU <= 41%); fusion triples FMA per staged
// byte and cuts HBM traffic 3x.
// FIX vs round-8: hedge stage 1 has the (xl < 15) guard. Without it,
// xl==15 threads wrote s1[y][182..191], aliasing s1[y+1][0..6] (the next
// row's replicate pad) -> write-write race in the same barrier phase.

#define HH 1024
#define WW 1024
#define BB 8
#define CC 3

struct GW181 { float w[181]; };                 // composed interior weights
struct GW3   { float a[61]; float b[61]; float c[61]; };  // w10,w20,w40

// ---------------------------------------------------------------------------
// Fused horizontal interior: out cols [90,934). Block = 32 rows x 128 cols.
// LDS tile 32 x 309 (stride 309 odd -> 2 lanes/bank, free).
// 256 thr = 32 y x 8 xg, 16 outputs/thread, sliding 196-step window.
// ---------------------------------------------------------------------------
__global__ __launch_bounds__(256) void hfused(const float* __restrict__ in,
                                              float* __restrict__ out, GW181 g) {
    __shared__ float tile[32][309];
    const int x0 = 90 + 128 * blockIdx.x;       // 0..6
    const int y0 = blockIdx.y * 32;             // 0..31
    const int bc = blockIdx.z;                  // 0..23
    const int t  = threadIdx.x;

    const float* __restrict__ src = in + ((size_t)bc * HH + y0) * WW;
    {   // stage 32 rows x 308 cols (u = x0-90+c; clamp only right edge)
        const int lane = t & 63, rg = t >> 6;
        #pragma unroll
        for (int k = 0; k < 8; ++k) {
            const int r = rg + 4 * k;
            const float* srow = src + (size_t)r * WW;
            #pragma unroll
            for (int m = 0; m < 5; ++m) {
                const int c = lane + 64 * m;
                if (c < 308) tile[r][c] = srow[min(x0 - 90 + c, WW - 1)];
            }
        }
    }
    __syncthreads();

    const int y = t & 31, xg = t >> 5;
    float acc[16];
    #pragma unroll
    for (int i = 0; i < 16; ++i) acc[i] = 0.f;

    #pragma unroll
    for (int j = 0; j < 196; ++j) {             // tilecol = xg*16 + i + tt
        const float v = tile[y][xg * 16 + j];
        #pragma unroll
        for (int i = 0; i < 16; ++i) {
            const int tt = j - i;
            if (tt >= 0 && tt < 181) acc[i] = fmaf(g.w[tt], v, acc[i]);
        }
    }

    float* drow = out + ((size_t)bc * HH + y0 + y) * WW + x0 + xg * 16;
    #pragma unroll
    for (int i = 0; i < 16; ++i)
        if (x0 + xg * 16 + i < 934) drow[i] = acc[i];
}

// ---------------------------------------------------------------------------
// Fused vertical interior: out rows [90,934). Block = 32 cols x 128 rows.
// LDS tile 308 x 32 (bank = col -> 2 lanes/bank, free). Staging and
// stores are 128 B coalesced (lanes span cols).
// ---------------------------------------------------------------------------
__global__ __launch_bounds__(256) void vfused(const float* __restrict__ in,
                                              float* __restrict__ out, GW181 g) {
    __shared__ float tile[308][32];
    const int Y0 = 90 + 128 * blockIdx.x;       // 0..6
    const int x0 = blockIdx.y * 32;             // 0..31
    const int bc = blockIdx.z;
    const int t  = threadIdx.x;

    const float* __restrict__ src = in + (size_t)bc * (HH * (size_t)WW);
    {   // stage 308 rows x 32 cols
        const int col = t & 31, rg = t >> 5;
        #pragma unroll
        for (int k = 0; k < 39; ++k) {
            const int r = rg + 8 * k;
            if (r < 308) {
                const int u = min(Y0 - 90 + r, HH - 1);
                tile[r][col] = src[(size_t)u * WW + x0 + col];
            }
        }
    }
    __syncthreads();

    const int col = t & 31, yo = (t >> 5) * 16;
    float acc[16];
    #pragma unroll
    for (int i = 0; i < 16; ++i) acc[i] = 0.f;

    #pragma unroll
    for (int j = 0; j < 196; ++j) {
        const float v = tile[yo + j][col];
        #pragma unroll
        for (int i = 0; i < 16; ++i) {
            const int tt = j - i;
            if (tt >= 0 && tt < 181) acc[i] = fmaf(g.w[tt], v, acc[i]);
        }
    }

    float* dst = out + (size_t)bc * (HH * (size_t)WW) + x0 + col;
    #pragma unroll
    for (int i = 0; i < 16; ++i) {
        const int yy = Y0 + yo + i;
        if (yy < 934) dst[(size_t)yy * WW] = acc[i];
    }
}

// ---------------------------------------------------------------------------
// Horizontal edge bands (x<90 and x>=934 via mirror): exact 3-stage chain
// computed in LDS. Block = 16 rows x one side. Phases: stage in ->
// A1=H10 (150 outs, 15 thr x 10) -> A2=H20 (120, 15 x 8) -> out=H40
// (90, 15 x 6). 32-col replicate pads keep compute clamp-free.
// ---------------------------------------------------------------------------
__global__ __launch_bounds__(256) void hedge(const float* __restrict__ in,
                                             float* __restrict__ out, GW3 g) {
    __shared__ float s0[16][217], s1[16][185], s2[16][153];
    const int ys   = blockIdx.x;                // 64 strips of 16 rows
    const int bc   = blockIdx.y;
    const int side = blockIdx.z;
    const int t    = threadIdx.x;

    const float* __restrict__ src = in + ((size_t)bc * HH + ys * 16) * WW;
    {   // stage: s0[r][c] = in(row, mirror(max(c-32,0)))
        const int lane = t & 63, rg = t >> 6;
        #pragma unroll
        for (int k = 0; k < 4; ++k) {
            const int r = rg + 4 * k;
            #pragma unroll
            for (int m = 0; m < 4; ++m) {
                const int c = lane + 64 * m;
                if (c < 217) {
                    int u = max(c - 32, 0);
                    if (side) u = WW - 1 - u;
                    s0[r][c] = src[(size_t)r * WW + u];
                }
            }
        }
    }
    __syncthreads();

    const int y = t >> 4, xl = t & 15;

    if (xl < 15) {  // A1(z) = sum_r w10[r] * in(z+r-30), z in [10*xl, +10)
        float a[10];
        #pragma unroll
        for (int i = 0; i < 10; ++i) a[i] = 0.f;
        const int z0 = 10 * xl;
        #pragma unroll
        for (int j = 0; j < 70; ++j) {
            const float v = s0[y][z0 + 2 + j];
            #pragma unroll
            for (int i = 0; i < 10; ++i) {
                const int r = j - i;
                if (r >= 0 && r < 61) a[i] = fmaf(g.a[r], v, a[i]);
            }
        }
        #pragma unroll
        for (int i = 0; i < 10; ++i) s1[y][z0 + 32 + i] = a[i];
        if (xl == 0)
            for (int p = 0; p < 32; ++p) s1[y][p] = a[0];   // replicate pad
    }
    __syncthreads();

    if (xl < 15) {  // A2(z) = sum_s w20[s] * A1(z+s-30), z in [8*xl, +8)
        float a[8];
        #pragma unroll
        for (int i = 0; i < 8; ++i) a[i] = 0.f;
        const int z0 = 8 * xl;
        #pragma unroll
        for (int j = 0; j < 68; ++j) {
            const float v = s1[y][z0 + 2 + j];
            #pragma unroll
            for (int i = 0; i < 8; ++i) {
                const int r = j - i;
                if (r >= 0 && r < 61) a[i] = fmaf(g.b[r], v, a[i]);
            }
        }
        #pragma unroll
        for (int i = 0; i < 8; ++i) s2[y][z0 + 32 + i] = a[i];
        if (xl == 0)
            for (int p = 0; p < 32; ++p) s2[y][p] = a[0];
    }
    __syncthreads();

    if (xl < 15) {  // out(x) = sum_t w40[t] * A2(x+t-30), x in [6*xl, +6)
        float a[6];
        #pragma unroll
        for (int i = 0; i < 6; ++i) a[i] = 0.f;
        const int z0 = 6 * xl;
        #pragma unroll
        for (int j = 0; j < 66; ++j) {
            const float v = s2[y][z0 + 2 + j];
            #pragma unroll
            for (int i = 0; i < 6; ++i) {
                const int r = j - i;
                if (r >= 0 && r < 61) a[i] = fmaf(g.c[r], v, a[i]);
            }
        }
        float* drow = out + ((size_t)bc * HH + ys * 16 + y) * WW;
        #pragma unroll
        for (int i = 0; i < 6; ++i) {
            const int gx = z0 + i;
            drow[side ? (WW - 1 - gx) : gx] = a[i];
        }
    }
}

// ---------------------------------------------------------------------------
// Vertical edge bands (y<90 and y>=934 via mirror): transposed hedge.
// Block = 16 cols x one side. LDS [rows][17] (stride 17, odd).
// ---------------------------------------------------------------------------
__global__ __launch_bounds__(256) void vedge(const float* __restrict__ in,
                                             float* __restrict__ out, GW3 g) {
    __shared__ float s0[217][17], s1[185][17], s2[153][17];
    const int xs   = blockIdx.x;                // 64 strips of 16 cols
    const int bc   = blockIdx.y;
    const int side = blockIdx.z;
    const int t    = threadIdx.x;
    const int cx   = t & 15, zl = t >> 4;

    const float* __restrict__ src = in + (size_t)bc * (HH * (size_t)WW);
    {   // stage: s0[r][cx] = in(mirror(max(r-32,0)), xs*16+cx)
        #pragma unroll
        for (int k = 0; k < 14; ++k) {
            const int r = zl + 16 * k;
            if (r < 217) {
                int u = max(r - 32, 0);
                if (side) u = HH - 1 - u;
                s0[r][cx] = src[(size_t)u * WW + xs * 16 + cx];
            }
        }
    }
    __syncthreads();

    if (zl < 15) {  // A1 rows [10*zl, +10)
        float a[10];
        #pragma unroll
        for (int i = 0; i < 10; ++i) a[i] = 0.f;
        const int z0 = 10 * zl;
        #pragma unroll
        for (int j = 0; j < 70; ++j) {
            const float v = s0[z0 + 2 + j][cx];
            #pragma unroll
            for (int i = 0; i < 10; ++i) {
                const int r = j - i;
                if (r >= 0 && r < 61) a[i] = fmaf(g.a[r], v, a[i]);
            }
        }
        #pragma unroll
        for (int i = 0; i < 10; ++i) s1[z0 + 32 + i][cx] = a[i];
        if (zl == 0)
            for (int p = 0; p < 32; ++p) s1[p][cx] = a[0];
    }
    __syncthreads();

    if (zl < 15) {  // A2 rows [8*zl, +8)
        float a[8];
        #pragma unroll
        for (int i = 0; i < 8; ++i) a[i] = 0.f;
        const int z0 = 8 * zl;
        #pragma unroll
        for (int j = 0; j < 68; ++j) {
            const float v = s1[z0 + 2 + j][cx];
            #pragma unroll
            for (int i = 0; i < 8; ++i) {
                const int r = j - i;
                if (r >= 0 && r < 61) a[i] = fmaf(g.b[r], v, a[i]);
            }
        }
        #pragma unroll
        for (int i = 0; i < 8; ++i) s2[z0 + 32 + i][cx] = a[i];
        if (zl == 0)
            for (int p = 0; p < 32; ++p) s2[p][cx] = a[0];
    }
    __syncthreads();

    if (zl < 15) {  // out rows [6*zl, +6)
        float a[6];
        #pragma unroll
        for (int i = 0; i < 6; ++i) a[i] = 0.f;
        const int z0 = 6 * zl;
        #pragma unroll
        for (int j = 0; j < 66; ++j) {
            const float v = s2[z0 + 2 + j][cx];
            #pragma unroll
            for (int i = 0; i < 6; ++i) {
                const int r = j - i;
                if (r >= 0 && r < 61) a[i] = fmaf(g.c[r], v, a[i]);
            }
        }
        #pragma unroll
        for (int i = 0; i < 6; ++i) {
            const int gy = z0 + i;
            const int Y  = side ? (HH - 1 - gy) : gy;
            out[(size_t)bc * (HH * (size_t)WW) + (size_t)Y * WW + xs * 16 + cx] = a[i];
        }
    }
}

// ---------------------------------------------------------------------------
static void gauss61(double sigma, double* w) {
    double s = 0.0;
    for (int k = 0; k < 61; ++k) {
        const double d = (double)(k - 30);
        w[k] = exp(-(d * d) / (2.0 * sigma * sigma));
        s += w[k];
    }
    for (int k = 0; k < 61; ++k) w[k] /= s;
}

extern "C" void kernel_launch(void* const* d_in, const int* in_sizes, int n_in,
                              void* d_out, int out_size, void* d_ws, size_t ws_size,
                              hipStream_t stream) {
    const float* input = (const float*)d_in[0];
    float* out = (float*)d_out;
    float* tmp = (float*)d_ws;                  // 96 MiB scratch (H result)

    double w10[61], w20[61], w40[61], c1[121], W[181];
    gauss61(10.0, w10); gauss61(20.0, w20); gauss61(40.0, w40);
    for (int k = 0; k < 121; ++k) c1[k] = 0.0;
    for (int i = 0; i < 61; ++i)
        for (int j = 0; j < 61; ++j) c1[i + j] += w10[i] * w20[j];
    for (int k = 0; k < 181; ++k) W[k] = 0.0;
    for (int i = 0; i < 121; ++i)
        for (int j = 0; j < 61; ++j) W[i + j] += c1[i] * w40[j];

    GW181 gi;
    for (int k = 0; k < 181; ++k) gi.w[k] = (float)W[k];
    GW3 ge;
    for (int k = 0; k < 61; ++k) {
        ge.a[k] = (float)w10[k];
        ge.b[k] = (float)w20[k];
        ge.c[k] = (float)w40[k];
    }

    const dim3 tb(256);
    const dim3 gh(7, 32, BB * CC);              // interior H: 5376 blocks
    const dim3 gv(7, 32, BB * CC);              // interior V
    const dim3 ge_h(64, BB * CC, 2);            // H edge bands
    const dim3 ge_v(64, BB * CC, 2);            // V edge bands

    hfused<<<gh, tb, 0, stream>>>(input, tmp, gi);
    hedge <<<ge_h, tb, 0, stream>>>(input, tmp, ge);
    vfused<<<gv, tb, 0, stream>>>(tmp, out, gi);
    vedge <<<ge_v, tb, 0, stream>>>(tmp, out, ge);
}